// Round 6
// baseline (5789.744 us; speedup 1.0000x reference)
//
#include <hip/hip_runtime.h>
#include <hip/hip_cooperative_groups.h>

typedef __bf16 bf16;
typedef __bf16 bf16x8 __attribute__((ext_vector_type(8)));
typedef float f32x4 __attribute__((ext_vector_type(4)));
typedef unsigned int u32;
typedef unsigned long long u64;
typedef unsigned int u32x4 __attribute__((ext_vector_type(4)));

// Problem dims
#define TT 256
#define NTAGS 50

// Workspace layout (bytes)
#define OFF_WIH   0ull                       // bf16 [1024][1024]
#define OFF_WHH   (OFF_WIH  + 2097152ull)
#define OFF_WCH   (OFF_WHH  + 2097152ull)
#define OFF_WC2H  (OFF_WCH  + 2097152ull)
#define OFF_DW    (OFF_WC2H + 2097152ull)    // bf16 [64][1024] (tags padded to 64)
#define OFF_XW    (OFF_DW   + 131072ull)     // bf16 [16384][1024]  x@Wih^T + b_ih + b_hh
#define OFF_HISTB (OFF_XW   + 33554432ull)   // bf16 [256][64][1024] hy(t+1) at slot t (k_out input)
#define OFF_HT    (OFF_HISTB + 33554432ull)  // u32 [2][64][1024] ticketed h: (tick<<16)|bf16
#define OFF_CT    (OFF_HT   + 524288ull)     // u32 [2][64][1024] ticketed c
// total ~73.1 MB

// Agent-scope relaxed (L2-bypassing, meet-at-L3) accessors.
__device__ __forceinline__ u64 cohload(const u64* p) {
  return __hip_atomic_load(p, __ATOMIC_RELAXED, __HIP_MEMORY_SCOPE_AGENT);
}
__device__ __forceinline__ void cohstore32(u32* p, u32 v) {
  __hip_atomic_store(p, v, __ATOMIC_RELAXED, __HIP_MEMORY_SCOPE_AGENT);
}
// u64 ticketed word -> packed 2xbf16 (low halves of each u32)
__device__ __forceinline__ u32 pack2(u64 w) {
  return (u32)(w & 0xFFFFu) | ((u32)(w >> 16) & 0xFFFF0000u);
}
__device__ __forceinline__ u32 tickbad(u64 w, u32 tick) {
  return ((((u32)(w >> 16)) ^ tick) & 0xFFFFu) | (((u32)(w >> 48)) ^ tick);
}

// ---------------- prep: weights->bf16, ticketed h0/c0 init, slot1 invalidate ----------------
__global__ void k_prep(const float* __restrict__ wih, const float* __restrict__ whh,
                       const float* __restrict__ wch, const float* __restrict__ wc2h,
                       const float* __restrict__ dw, const float* __restrict__ h0,
                       const float* __restrict__ c0, char* __restrict__ ws) {
  const long N_W = 4194304, N_DW = 65536, N_S = 65536;
  const long TOT = N_W + N_DW + 4 * N_S;
  long stride = (long)gridDim.x * blockDim.x;
  for (long idx = (long)blockIdx.x * blockDim.x + threadIdx.x; idx < TOT; idx += stride) {
    if (idx < N_W) {
      long m = idx >> 20, e = idx & 1048575;
      const float* s = (m == 0) ? wih : (m == 1) ? whh : (m == 2) ? wch : wc2h;
      ((bf16*)(ws + OFF_WIH))[idx] = (bf16)s[e];
    } else if (idx < N_W + N_DW) {
      long j = idx - N_W; long r = j >> 10, e = j & 1023;
      ((bf16*)(ws + OFF_DW))[j] = (bf16)((r < NTAGS) ? dw[r * 1024 + e] : 0.f);
    } else if (idx < N_W + N_DW + N_S) {          // HT slot0 = h0, ticket 0
      long j = idx - N_W - N_DW;
      ((u32*)(ws + OFF_HT))[j] = (u32)__builtin_bit_cast(unsigned short, (bf16)h0[j]);
    } else if (idx < N_W + N_DW + 2 * N_S) {      // HT slot1 = invalid ticket
      long j = idx - N_W - N_DW - N_S;
      ((u32*)(ws + OFF_HT))[N_S + j] = 0xFFFF0000u;
    } else if (idx < N_W + N_DW + 3 * N_S) {      // CT slot0 = c0, ticket 0
      long j = idx - N_W - N_DW - 2 * N_S;
      ((u32*)(ws + OFF_CT))[j] = (u32)__builtin_bit_cast(unsigned short, (bf16)c0[j]);
    } else {                                      // CT slot1 = invalid ticket
      long j = idx - N_W - N_DW - 3 * N_S;
      ((u32*)(ws + OFF_CT))[N_S + j] = 0xFFFF0000u;
    }
  }
}

// ---------------- XW = emb[X] @ Wih^T + b_ih + b_hh  (gather fused) ----------------
__global__ __launch_bounds__(256) void k_xw(const int* __restrict__ X,
                                            const float* __restrict__ emb,
                                            const float* __restrict__ b_ih,
                                            const float* __restrict__ b_hh,
                                            char* __restrict__ ws) {
  const bf16* wih = (const bf16*)(ws + OFF_WIH);
  bf16* xw = (bf16*)(ws + OFF_XW);
  int l = threadIdx.x & 63, wv = threadIdx.x >> 6;
  int i0 = blockIdx.x * 64 + wv * 16;
  int h0 = blockIdx.y * 64;
  const float* ap = emb + (long)X[i0 + (l & 15)] * 1024 + ((l >> 4) * 8);
  const bf16* bp = wih + (long)(h0 + (l & 15)) * 1024 + ((l >> 4) * 8);
  f32x4 zero = {0.f, 0.f, 0.f, 0.f};
  f32x4 acc[4] = {zero, zero, zero, zero};
  for (int k = 0; k < 1024; k += 32) {
    f32x4 f0 = *(const f32x4*)(ap + k);
    f32x4 f1 = *(const f32x4*)(ap + k + 4);
    bf16x8 a;
#pragma unroll
    for (int q = 0; q < 4; ++q) { a[q] = (bf16)f0[q]; a[4 + q] = (bf16)f1[q]; }
#pragma unroll
    for (int j = 0; j < 4; ++j) {
      bf16x8 b = *(const bf16x8*)(bp + j * 16 * 1024 + k);
      acc[j] = __builtin_amdgcn_mfma_f32_16x16x32_bf16(a, b, acc[j], 0, 0, 0);
    }
  }
#pragma unroll
  for (int j = 0; j < 4; ++j)
#pragma unroll
    for (int r = 0; r < 4; ++r) {
      int row = i0 + (l >> 4) * 4 + r;
      int col = h0 + j * 16 + (l & 15);
      xw[(long)row * 1024 + col] = (bf16)(acc[j][r] + b_ih[col] + b_hh[col]);
    }
}

// ---------------- recurrence: barrier-FREE ticketed dataflow ----------------
// group g = blockIdx&3 owns batch rows [16g,16g+16); block j = blockIdx>>2 owns h-slice
// [16j,16j+16). 4 waves K-split (256 each). Every cross-block element is a u32
// (ticket<<16 | bf16): producer's single relaxed agent store publishes data+version
// atomically; consumers poll exact tickets. One L3 round trip per phase, no fences,
// no vmcnt drains, no flags. Safety of slot reuse follows from the all-to-all data
// dependency per phase (writer at t+2 transitively follows all readers of t).
__global__ __launch_bounds__(256, 1) void k_rnn(const float* __restrict__ b_ch,
                                                const float* __restrict__ b_c2h,
                                                const float* __restrict__ c0,
                                                char* __restrict__ ws) {
  const bf16* xw = (const bf16*)(ws + OFF_XW);
  bf16* histb = (bf16*)(ws + OFF_HISTB);
  u32* HT = (u32*)(ws + OFF_HT);
  u32* CT = (u32*)(ws + OFF_CT);
  int g = blockIdx.x & 3, j = blockIdx.x >> 2;

  int l = threadIdx.x & 63, wv = threadIdx.x >> 6;
  int b0 = g * 16, h0b = j * 16;
  int e = threadIdx.x;
  int eoff = (b0 + (e >> 4)) * 1024 + h0b + (e & 15);
  int gh = h0b + (e & 15);

  __shared__ float red[4][2][256];

  int lane_r = l & 15;
  int koff = wv * 256 + ((l >> 4) * 8);
  long arow = (long)(b0 + lane_r) * 1024 + koff;   // element offset within one slot

  const bf16* whh_p  = (const bf16*)(ws + OFF_WHH)  + (long)(h0b + lane_r) * 1024 + koff;
  const bf16* wch_p  = (const bf16*)(ws + OFF_WCH)  + (long)(h0b + lane_r) * 1024 + koff;
  const bf16* wc2h_p = (const bf16*)(ws + OFF_WC2H) + (long)(h0b + lane_r) * 1024 + koff;

  float bch_v = b_ch[gh], bc2h_v = b_c2h[gh];
  float c_reg = c0[eoff];
  f32x4 zero = {0.f, 0.f, 0.f, 0.f};

  for (int t = 0; t < TT; ++t) {
    u32 tk = (u32)t, tk1 = (u32)(t + 1);
    const u64* hp  = (const u64*)(HT + (long)(t & 1) * 65536 + arow);
    const u64* cp  = (const u64*)(CT + (long)(t & 1) * 65536 + arow);
    float xwv = (float)xw[(long)t * 65536 + eoff];   // issue early (L2/L3, off poll path)

    // ---- phase A: poll h(t) (written last), then c(t); pack; MFMA
    u64 buf[32];
    bf16x8 a1f[8], a2f[8];
    for (;;) {   // h(t)
#pragma unroll
      for (int i = 0; i < 8; ++i)
#pragma unroll
        for (int q = 0; q < 4; ++q) buf[i * 4 + q] = cohload(hp + i * 16 + q);
      u32 bad = 0;
#pragma unroll
      for (int i = 0; i < 32; ++i) bad |= tickbad(buf[i], tk);
      if (!__any(bad)) break;
      __builtin_amdgcn_s_sleep(1);
    }
#pragma unroll
    for (int i = 0; i < 8; ++i) {
      u32x4 p = {pack2(buf[i * 4]), pack2(buf[i * 4 + 1]), pack2(buf[i * 4 + 2]), pack2(buf[i * 4 + 3])};
      a1f[i] = __builtin_bit_cast(bf16x8, p);
    }
    for (;;) {   // c(t) — produced one phase earlier, nearly always ready
#pragma unroll
      for (int i = 0; i < 8; ++i)
#pragma unroll
        for (int q = 0; q < 4; ++q) buf[i * 4 + q] = cohload(cp + i * 16 + q);
      u32 bad = 0;
#pragma unroll
      for (int i = 0; i < 32; ++i) bad |= tickbad(buf[i], tk);
      if (!__any(bad)) break;
      __builtin_amdgcn_s_sleep(1);
    }
#pragma unroll
    for (int i = 0; i < 8; ++i) {
      u32x4 p = {pack2(buf[i * 4]), pack2(buf[i * 4 + 1]), pack2(buf[i * 4 + 2]), pack2(buf[i * 4 + 3])};
      a2f[i] = __builtin_bit_cast(bf16x8, p);
    }
    f32x4 ap_ = zero, ac_ = zero;
#pragma unroll
    for (int kk = 0; kk < 8; ++kk) {
      ap_ = __builtin_amdgcn_mfma_f32_16x16x32_bf16(a1f[kk], *(const bf16x8*)(whh_p + kk * 32), ap_, 0, 0, 0);
      ac_ = __builtin_amdgcn_mfma_f32_16x16x32_bf16(a2f[kk], *(const bf16x8*)(wch_p + kk * 32), ac_, 0, 0, 0);
    }
#pragma unroll
    for (int r = 0; r < 4; ++r) {
      int ei = ((l >> 4) * 4 + r) * 16 + (l & 15);
      red[wv][0][ei] = ap_[r];
      red[wv][1][ei] = ac_[r];
    }
    __syncthreads();
    float pre = red[0][0][e] + red[1][0][e] + red[2][0][e] + red[3][0][e] + xwv;
    float cgm = red[0][1][e] + red[1][1][e] + red[2][1][e] + red[3][1][e] + bch_v;
    float gif = 1.f / (1.f + expf(-(pre + cgm)));
    float cy = gif * (c_reg + tanhf(pre));
    c_reg = cy;
    cohstore32(CT + (long)((t + 1) & 1) * 65536 + eoff,
               (tk1 << 16) | (u32)__builtin_bit_cast(unsigned short, (bf16)cy));
    __syncthreads();   // red reads done before phase B rewrites red

    // ---- phase B: poll cy(t+1), MFMA with Wc2h
    const u64* cyp = (const u64*)(CT + (long)((t + 1) & 1) * 65536 + arow);
    for (;;) {
#pragma unroll
      for (int i = 0; i < 8; ++i)
#pragma unroll
        for (int q = 0; q < 4; ++q) buf[i * 4 + q] = cohload(cyp + i * 16 + q);
      u32 bad = 0;
#pragma unroll
      for (int i = 0; i < 32; ++i) bad |= tickbad(buf[i], tk1);
      if (!__any(bad)) break;
      __builtin_amdgcn_s_sleep(1);
    }
#pragma unroll
    for (int i = 0; i < 8; ++i) {
      u32x4 p = {pack2(buf[i * 4]), pack2(buf[i * 4 + 1]), pack2(buf[i * 4 + 2]), pack2(buf[i * 4 + 3])};
      a1f[i] = __builtin_bit_cast(bf16x8, p);
    }
    f32x4 ao = zero;
#pragma unroll
    for (int kk = 0; kk < 8; ++kk)
      ao = __builtin_amdgcn_mfma_f32_16x16x32_bf16(a1f[kk], *(const bf16x8*)(wc2h_p + kk * 32), ao, 0, 0, 0);
#pragma unroll
    for (int r = 0; r < 4; ++r)
      red[wv][0][((l >> 4) * 4 + r) * 16 + (l & 15)] = ao[r];
    __syncthreads();
    float o = red[0][0][e] + red[1][0][e] + red[2][0][e] + red[3][0][e] + bc2h_v;
    float og = 1.f / (1.f + expf(-(pre + o)));
    bf16 hb = (bf16)(og * tanhf(cy));
    cohstore32(HT + (long)((t + 1) & 1) * 65536 + eoff,
               (tk1 << 16) | (u32)__builtin_bit_cast(unsigned short, hb));
    histb[(long)t * 65536 + eoff] = hb;   // plain copy for k_out (kernel-boundary coherent)
    __syncthreads();   // red reads done before next iter's phase A rewrites red
  }
}

// ---------------- dense + softmax ----------------
__global__ __launch_bounds__(256) void k_out(const float* __restrict__ dense_b,
                                             const char* __restrict__ ws,
                                             float* __restrict__ out) {
  const bf16* h  = (const bf16*)(ws + OFF_HISTB);  // slot t = hy(t+1) = row block t
  const bf16* dw = (const bf16*)(ws + OFF_DW);
  int l = threadIdx.x & 63, wv = threadIdx.x >> 6;
  int i0 = blockIdx.x * 64 + wv * 16;
  const bf16* ap = h  + (long)(i0 + (l & 15)) * 1024 + ((l >> 4) * 8);
  const bf16* bp = dw + (long)(l & 15) * 1024 + ((l >> 4) * 8);
  f32x4 zero = {0.f, 0.f, 0.f, 0.f};
  f32x4 acc[4] = {zero, zero, zero, zero};
  for (int k = 0; k < 1024; k += 32) {
    bf16x8 a = *(const bf16x8*)(ap + k);
#pragma unroll
    for (int j = 0; j < 4; ++j) {
      bf16x8 b = *(const bf16x8*)(bp + j * 16 * 1024 + k);
      acc[j] = __builtin_amdgcn_mfma_f32_16x16x32_bf16(a, b, acc[j], 0, 0, 0);
    }
  }
  int tag0 = l & 15;
#pragma unroll
  for (int r = 0; r < 4; ++r) {
    int row = i0 + (l >> 4) * 4 + r;
    float lg[4], ex[4];
    float mx = -1e30f;
#pragma unroll
    for (int j = 0; j < 4; ++j) {
      int tag = j * 16 + tag0;
      lg[j] = (tag < NTAGS) ? (acc[j][r] + dense_b[tag]) : -1e30f;
      mx = fmaxf(mx, lg[j]);
    }
    for (int m = 1; m < 16; m <<= 1) mx = fmaxf(mx, __shfl_xor(mx, m, 64));
    float s = 0.f;
#pragma unroll
    for (int j = 0; j < 4; ++j) {
      int tag = j * 16 + tag0;
      ex[j] = (tag < NTAGS) ? expf(lg[j] - mx) : 0.f;
      s += ex[j];
    }
    for (int m = 1; m < 16; m <<= 1) s += __shfl_xor(s, m, 64);
    float inv = 1.f / s;
#pragma unroll
    for (int j = 0; j < 4; ++j) {
      int tag = j * 16 + tag0;
      if (tag < NTAGS) out[(long)row * 50 + tag] = ex[j] * inv;
    }
  }
}

extern "C" void kernel_launch(void* const* d_in, const int* in_sizes, int n_in,
                              void* d_out, int out_size, void* d_ws, size_t ws_size,
                              hipStream_t stream) {
  const int*   X        = (const int*)d_in[0];
  // d_in[1] = lengths (unused; all == T)
  const float* embedding = (const float*)d_in[2];
  const float* w_ih  = (const float*)d_in[3];
  const float* w_hh  = (const float*)d_in[4];
  const float* w_ch  = (const float*)d_in[5];
  const float* w_c2h = (const float*)d_in[6];
  const float* b_ih  = (const float*)d_in[7];
  const float* b_hh  = (const float*)d_in[8];
  const float* b_ch  = (const float*)d_in[9];
  const float* b_c2h = (const float*)d_in[10];
  const float* dense_w = (const float*)d_in[11];
  const float* dense_b = (const float*)d_in[12];
  const float* h0 = (const float*)d_in[13];
  const float* c0 = (const float*)d_in[14];
  char* ws = (char*)d_ws;
  float* out = (float*)d_out;

  k_prep<<<2048, 256, 0, stream>>>(w_ih, w_hh, w_ch, w_c2h, dense_w, h0, c0, ws);
  k_xw<<<dim3(256, 16), 256, 0, stream>>>(X, embedding, b_ih, b_hh, ws);

  void* args[] = {(void*)&b_ch, (void*)&b_c2h, (void*)&c0, (void*)&ws};
  hipLaunchCooperativeKernel((const void*)k_rnn, dim3(256), dim3(256), args, 0, stream);

  k_out<<<256, 256, 0, stream>>>(dense_b, ws, out);
}